// Round 5
// baseline (206.056 us; speedup 1.0000x reference)
//
#include <hip/hip_runtime.h>
#include <stdint.h>

#define N_ 8192
#define D_ 1024
// logit = dot(imn,capn)/T; fp8 operands pre-scaled by 16 -> acc = 256*dot
// (MX scales set to E8M0 1.0 -> identical numerics to plain fp8 MFMA)
#define EPILOGUE_SCALE (10.0f / 256.0f)
#define ENC_SCALE 16.0f
#define CHUNK 524288  // bytes of one K-chunk (64 K-bytes x 8192 rows): 256 T32-tiles x 2048B

typedef float f32x4 __attribute__((ext_vector_type(4)));
typedef float f32x16 __attribute__((ext_vector_type(16)));
typedef int i32x4 __attribute__((ext_vector_type(4)));
typedef int i32x8 __attribute__((ext_vector_type(8)));

// async global->LDS, 16B per lane, LDS dest = wave-uniform base + lane*16
#define GLD16(gsrc, ldst)                                                    \
  __builtin_amdgcn_global_load_lds(                                          \
      (const __attribute__((address_space(1))) unsigned int*)(gsrc),         \
      (__attribute__((address_space(3))) unsigned int*)(ldst), 16, 0, 0)

// R4 fragment layout (32x32x64 f8f6f4 family pattern), both operands, 8MB:
//   byte addr = c*524288 + T32*2048 + p*1024 + l*16 + o   (c:K-chunk of 64,
//   T32: 32-row tile, p: K-16B-half, l: lane, o in [0,16))
//   holds row = T32*32 + (l&31), k = c*64 + (l>>5)*32 + p*16 + o.

// Kernel 1 [unchanged]: normalize + fp8 encode, fragment-layout stores.
__global__ __launch_bounds__(1024) void normalize_k(
    const float* __restrict__ im, const float* __restrict__ cap,
    unsigned int* __restrict__ imn, unsigned int* __restrict__ capn,
    float* __restrict__ diag, float* __restrict__ sums /* rowsum|colsum */) {
  __shared__ unsigned int ldsA[16 * 260];  // stride 260: 16B-aligned rows
  __shared__ unsigned int ldsB[16 * 260];
  const int til = blockIdx.x;
  const int t = threadIdx.x;
  if (til < 4) ((float4*)sums)[til * 1024 + t] = (float4){0.f, 0.f, 0.f, 0.f};

  const int r = t >> 6, j = t & 63;   // wave r = row r of tile; lane j
  const int row = til * 16 + r;
  const float4* __restrict__ aR = (const float4*)(im + (size_t)row * D_);
  const float4* __restrict__ bR = (const float4*)(cap + (size_t)row * D_);

  float4 a0 = aR[j], a1 = aR[j + 64], a2 = aR[j + 128], a3 = aR[j + 192];
  float4 b0 = bR[j], b1 = bR[j + 64], b2 = bR[j + 128], b3 = bR[j + 192];

  float ssa = a0.x * a0.x + a0.y * a0.y + a0.z * a0.z + a0.w * a0.w
            + a1.x * a1.x + a1.y * a1.y + a1.z * a1.z + a1.w * a1.w
            + a2.x * a2.x + a2.y * a2.y + a2.z * a2.z + a2.w * a2.w
            + a3.x * a3.x + a3.y * a3.y + a3.z * a3.z + a3.w * a3.w;
  float ssb = b0.x * b0.x + b0.y * b0.y + b0.z * b0.z + b0.w * b0.w
            + b1.x * b1.x + b1.y * b1.y + b1.z * b1.z + b1.w * b1.w
            + b2.x * b2.x + b2.y * b2.y + b2.z * b2.z + b2.w * b2.w
            + b3.x * b3.x + b3.y * b3.y + b3.z * b3.z + b3.w * b3.w;
  float dt  = a0.x * b0.x + a0.y * b0.y + a0.z * b0.z + a0.w * b0.w
            + a1.x * b1.x + a1.y * b1.y + a1.z * b1.z + a1.w * b1.w
            + a2.x * b2.x + a2.y * b2.y + a2.z * b2.z + a2.w * b2.w
            + a3.x * b3.x + a3.y * b3.y + a3.z * b3.z + a3.w * b3.w;
#pragma unroll
  for (int o = 1; o < 64; o <<= 1) {  // full-wave butterfly (row = 1 wave)
    ssa += __shfl_xor(ssa, o, 64);
    ssb += __shfl_xor(ssb, o, 64);
    dt  += __shfl_xor(dt, o, 64);
  }
  const float ra = rsqrtf(ssa), rb = rsqrtf(ssb);
  if (j == 0) diag[row] = dt * ra * rb * 10.0f;
  const float sa = ra * ENC_SCALE, sb = rb * ENC_SCALE;

#define CVT_ST(av, bv, ofs)                                                  \
  {                                                                          \
    int pa_ = __builtin_amdgcn_cvt_pk_fp8_f32(av.x * sa, av.y * sa, 0, false); \
    pa_ = __builtin_amdgcn_cvt_pk_fp8_f32(av.z * sa, av.w * sa, pa_, true);  \
    int pb_ = __builtin_amdgcn_cvt_pk_fp8_f32(bv.x * sb, bv.y * sb, 0, false); \
    pb_ = __builtin_amdgcn_cvt_pk_fp8_f32(bv.z * sb, bv.w * sb, pb_, true);  \
    ldsA[r * 260 + j + (ofs)] = (unsigned int)pa_;                           \
    ldsB[r * 260 + j + (ofs)] = (unsigned int)pb_;                           \
  }
  CVT_ST(a0, b0, 0)
  CVT_ST(a1, b1, 64)
  CVT_ST(a2, b2, 128)
  CVT_ST(a3, b3, 192)
#undef CVT_ST
  __syncthreads();

  // phase 3: thread t emits 16B granule q = t>>4 of row rp = t&15.
  {
    const int q = t >> 4, rp = t & 15;
    const uint4 va = *(const uint4*)&ldsA[rp * 260 + q * 4];
    const uint4 vb = *(const uint4*)&ldsB[rp * 260 + q * 4];
    const int row32 = ((til & 1) << 4) + rp;
    const size_t d = (size_t)(q >> 2) * CHUNK + (size_t)(til >> 1) * 2048
                   + (size_t)((q & 1) << 10)
                   + (size_t)((((q >> 1) & 1) << 5) + row32) * 16;
    *(uint4*)((unsigned char*)imn + d) = va;
    *(uint4*)((unsigned char*)capn + d) = vb;
  }
}

// Kernel 2 [R16]: LDS-read-wall fix. R4 was ds_read_b128-pipe-bound
// (128KB frag reads/CU-chunk at 85 B/cyc = measured 1757cyc/CU-chunk;
// MFMA needs only 1100 -> MfmaUtil 30%). Change: 4-wave blocks, tile
// 128(M)x256(N), wave tile 128x64 (acc[4][2] f32x16 = 128 AGPR). A (shared
// by all 4 waves) stays in LDS ring-2 (8KB/chunk); B (read by exactly ONE
// wave each) bypasses LDS entirely -> direct L2->reg, double-buffered in
// named reg sets. LDS/CU-chunk drops 176KB->80KB; MFMA becomes the binding
// pipe. Counted vmcnt(6) = 2 GLD16 + 4 B-loads per chunk, never 0 in-loop.
// 2 blocks/CU (LDS 2x16KB; ~100 VGPR + 128 AGPR at 2 waves/SIMD).
__global__ __launch_bounds__(256, 2) void gemm_lse_k(
    const unsigned char* __restrict__ A,   // fragment-layout imn
    const unsigned char* __restrict__ B,   // fragment-layout capn
    float* __restrict__ rowsum, float* __restrict__ colsum) {
  __shared__ unsigned char lds[2][8192];  // ring-2 A tiles: 4 T32 x 2048B
  const int t = threadIdx.x;
  const int w = t >> 6, l = t & 63;
  const int l16 = l * 16;

  // XCD swizzle: 256-block chunk per XCD; 8 rowT x 32 colT per chunk.
  const int bid = blockIdx.x + (blockIdx.y << 6);     // 0..2047
  const int nid = (bid & 7) * 256 + (bid >> 3);       // bijective (2048%8==0)
  const int rowT = ((nid >> 8) << 3) + (nid & 7);     // 0..63  (128-row tiles)
  const int colT = (nid >> 3) & 31;                   // 0..31  (256-col tiles)

  const size_t baseA = (size_t)rowT * 8192;   // 4 T32-tiles x 2048B per chunk
  const size_t baseB = (size_t)colT * 16384;  // 8 T32-tiles x 2048B per chunk

  // A staging: 8KB/chunk = 8 x 1KB; wave w owns 2 (o = w*2048 + {0,1024}).
  const unsigned char* __restrict__ srcA0 = A + baseA + w * 2048 + l16;
  const unsigned char* __restrict__ srcA1 = srcA0 + 1024;
  const int ofsA0 = w * 2048, ofsA1 = ofsA0 + 1024;

  // B: wave w owns cols [w*64, w*64+64) = T32 tiles w*2+{0,1}; per chunk
  // 4 x 16B/lane loads (n,h), direct from global (L2-resident, 8MB).
  const unsigned char* __restrict__ srcB = B + baseB + w * 4096 + l16;

#define STAGE(kc, buf)                                                       \
  {                                                                          \
    const size_t kofs = (size_t)(kc) * CHUNK;                                \
    GLD16(srcA0 + kofs, &lds[buf][ofsA0]);                                   \
    GLD16(srcA1 + kofs, &lds[buf][ofsA1]);                                   \
  }

#define BLOAD(dst, kc)                                                       \
  {                                                                          \
    const unsigned char* bp = srcB + (size_t)(kc) * CHUNK;                   \
    dst[0] = *(const i32x4*)(bp);                                            \
    dst[1] = *(const i32x4*)(bp + 1024);                                     \
    dst[2] = *(const i32x4*)(bp + 2048);                                     \
    dst[3] = *(const i32x4*)(bp + 3072);                                     \
  }

  f32x16 acc[4][2];
#pragma unroll
  for (int m = 0; m < 4; ++m)
#pragma unroll
    for (int n = 0; n < 2; ++n)
#pragma unroll
      for (int r = 0; r < 16; ++r) acc[m][n][r] = 0.f;

  i32x4 bb0[4], bb1[4];  // named double-buffer (rule #20: no runtime index)

#define COMPUTE(buf, bset)                                                   \
  {                                                                          \
    const unsigned char* Lc = &lds[buf][0];                                  \
    i32x8 a_[4], b_[2];                                                      \
    _Pragma("unroll")                                                        \
    for (int m = 0; m < 4; ++m) {                                            \
      i32x4 lo = *(const i32x4*)(Lc + m * 2048 + l16);                       \
      i32x4 hi = *(const i32x4*)(Lc + m * 2048 + 1024 + l16);                \
      a_[m] = __builtin_shufflevector(lo, hi, 0, 1, 2, 3, 4, 5, 6, 7);       \
    }                                                                        \
    b_[0] = __builtin_shufflevector(bset[0], bset[1], 0, 1, 2, 3, 4, 5, 6, 7); \
    b_[1] = __builtin_shufflevector(bset[2], bset[3], 0, 1, 2, 3, 4, 5, 6, 7); \
    _Pragma("unroll")                                                        \
    for (int m = 0; m < 4; ++m)                                              \
      _Pragma("unroll")                                                      \
      for (int n = 0; n < 2; ++n)                                            \
        acc[m][n] = __builtin_amdgcn_mfma_scale_f32_32x32x64_f8f6f4(         \
            a_[m], b_[n], acc[m][n], 0, 0, 0, 0x7F7F7F7F, 0, 0x7F7F7F7F);    \
  }

  // prologue: chunk 0 in flight (2 GLD + 4 B-loads)
  STAGE(0, 0)
  BLOAD(bb0, 0)

  // main loop, unrolled x2 (named B buffers). Per half: issue next chunk's
  // 6 vmem ops, then vmcnt(6) retires the current chunk's; A-buffer safety
  // via the two barriers (GLD16 to buf X issued only after the barrier that
  // closes COMPUTE on buf X).
#pragma unroll 1
  for (int kt = 0; kt < 14; kt += 2) {
    STAGE(kt + 1, (kt + 1) & 1)
    BLOAD(bb1, kt + 1)
    asm volatile("s_waitcnt vmcnt(6)" ::: "memory");
    __builtin_amdgcn_s_barrier();
    COMPUTE(kt & 1, bb0)
    __builtin_amdgcn_s_barrier();
    STAGE(kt + 2, (kt + 2) & 1)
    BLOAD(bb0, kt + 2)
    asm volatile("s_waitcnt vmcnt(6)" ::: "memory");
    __builtin_amdgcn_s_barrier();
    COMPUTE((kt + 1) & 1, bb1)
    __builtin_amdgcn_s_barrier();
  }
  // tail: chunks 14 (in bb0/buf0 path) and 15
  STAGE(15, 1)
  BLOAD(bb1, 15)
  asm volatile("s_waitcnt vmcnt(6)" ::: "memory");
  __builtin_amdgcn_s_barrier();
  COMPUTE(0, bb0)
  __builtin_amdgcn_s_barrier();
  asm volatile("s_waitcnt vmcnt(0)" ::: "memory");
  __builtin_amdgcn_s_barrier();
  COMPUTE(1, bb1)
#undef COMPUTE
#undef BLOAD
#undef STAGE

  // epilogue: exp (fixed-max LSE; |logit| <= 10, no overflow possible)
#pragma unroll
  for (int m = 0; m < 4; ++m)
#pragma unroll
    for (int n = 0; n < 2; ++n)
#pragma unroll
      for (int r = 0; r < 16; ++r)
        acc[m][n][r] = __expf(acc[m][n][r] * EPILOGUE_SCALE);

  // 32x32 C/D layout: col = lane&31, row = (reg&3)+8*(reg>>2)+4*(lane>>5)
  // [measured m74/m101]
  const int rowBase = rowT * 128;
  const int colBase = colT * 256 + w * 64;
#pragma unroll
  for (int m = 0; m < 4; ++m) {
    f32x16 s = acc[m][0] + acc[m][1];  // sum this wave's 64 cols elementwise
#pragma unroll
    for (int r = 0; r < 16; ++r) {
      float v = s[r];
      v += __shfl_xor(v, 1, 64);
      v += __shfl_xor(v, 2, 64);
      v += __shfl_xor(v, 4, 64);
      v += __shfl_xor(v, 8, 64);
      v += __shfl_xor(v, 16, 64);
      if ((l & 31) == 0)
        atomicAdd(&rowsum[rowBase + m * 32 + (r & 3) + 8 * (r >> 2) + 4 * (l >> 5)], v);
    }
  }
#pragma unroll
  for (int n = 0; n < 2; ++n) {
    float v = 0.f;
#pragma unroll
    for (int r = 0; r < 16; ++r) v += acc[0][n][r] + acc[1][n][r]
                                    + acc[2][n][r] + acc[3][n][r];
    v += __shfl_xor(v, 32, 64);  // combine the two row-half lane groups
    if (l < 32)
      atomicAdd(&colsum[colBase + n * 32 + l], v);
  }
}

// Kernel 3: scalar reduce. [unchanged]
__global__ __launch_bounds__(256) void finalize_k(
    const float* __restrict__ rowsum, const float* __restrict__ colsum,
    const float* __restrict__ diag, float* __restrict__ out) {
  const int t = threadIdx.x;
  float lse = 0.f, dg = 0.f;
  for (int i = t; i < N_; i += 256) {
    lse += __logf(rowsum[i]) + __logf(colsum[i]);
    dg += diag[i];
  }
#pragma unroll
  for (int o = 32; o > 0; o >>= 1) {
    lse += __shfl_down(lse, o, 64);
    dg  += __shfl_down(dg, o, 64);
  }
  __shared__ float red[2][4];
  const int w = t >> 6, l = t & 63;
  if (l == 0) { red[0][w] = lse; red[1][w] = dg; }
  __syncthreads();
  if (t == 0) {
    lse = red[0][0] + red[0][1] + red[0][2] + red[0][3];
    dg  = red[1][0] + red[1][1] + red[1][2] + red[1][3];
    out[0] = 0.5f * lse / (float)N_ - dg / (float)N_;
  }
}

extern "C" void kernel_launch(void* const* d_in, const int* in_sizes, int n_in,
                              void* d_out, int out_size, void* d_ws, size_t ws_size,
                              hipStream_t stream) {
  const float* im = (const float*)d_in[0];
  const float* cap = (const float*)d_in[1];
  float* out = (float*)d_out;
  char* ws = (char*)d_ws;
  unsigned char* imn = (unsigned char*)ws;                 // 8 MB fp8 (fragment layout)
  unsigned char* capn = imn + (size_t)N_ * D_;             // 8 MB fp8 (fragment layout)
  float* rowsum = (float*)(ws + 2 * (size_t)N_ * D_);
  float* colsum = rowsum + N_;
  float* diag = colsum + N_;

  normalize_k<<<512, 1024, 0, stream>>>(im, cap, (unsigned int*)imn,
                                        (unsigned int*)capn, diag, rowsum);
  gemm_lse_k<<<dim3(64, 32), 256, 0, stream>>>(imn, capn, rowsum, colsum);
  finalize_k<<<1, 256, 0, stream>>>(rowsum, colsum, diag, out);
}

// Round 6
// 203.088 us; speedup vs baseline: 1.0146x; 1.0146x over previous
//
#include <hip/hip_runtime.h>
#include <stdint.h>

#define N_ 8192
#define D_ 1024
// logit = dot(imn,capn)/T; fp8 operands pre-scaled by 16 -> acc = 256*dot
// (MX scales set to E8M0 1.0 -> identical numerics to plain fp8 MFMA)
#define EPILOGUE_SCALE (10.0f / 256.0f)
#define ENC_SCALE 16.0f
#define CHUNK 524288  // bytes of one K-chunk (64 K-bytes x 8192 rows): 256 T32-tiles x 2048B

typedef float f32x4 __attribute__((ext_vector_type(4)));
typedef float f32x16 __attribute__((ext_vector_type(16)));
typedef int i32x4 __attribute__((ext_vector_type(4)));
typedef int i32x8 __attribute__((ext_vector_type(8)));

// async global->LDS, 16B per lane, LDS dest = wave-uniform base + lane*16
#define GLD16(gsrc, ldst)                                                    \
  __builtin_amdgcn_global_load_lds(                                          \
      (const __attribute__((address_space(1))) unsigned int*)(gsrc),         \
      (__attribute__((address_space(3))) unsigned int*)(ldst), 16, 0, 0)

// imn layout (A, unchanged R4 fragment layout, GLD16-friendly):
//   byte addr = c*CHUNK + T32*2048 + p*1024 + l*16 + o
//   -> row = T32*32 + (l&31), k = c*64 + (l>>5)*32 + p*16 + o,  o in [0,16)
// capn layout (B, NEW lane-contiguous 32B so one i32x8 load = full fragment):
//   byte addr = c*CHUNK + T32*2048 + l*32 + o,  o in [0,32)
//   -> col = T32*32 + (l&31), k = c*64 + (l>>5)*32 + o

// Kernel 1: normalize + fp8 encode. Only the capn store formula changed.
__global__ __launch_bounds__(1024) void normalize_k(
    const float* __restrict__ im, const float* __restrict__ cap,
    unsigned int* __restrict__ imn, unsigned int* __restrict__ capn,
    float* __restrict__ diag, float* __restrict__ sums /* rowsum|colsum */) {
  __shared__ unsigned int ldsA[16 * 260];  // stride 260: 16B-aligned rows
  __shared__ unsigned int ldsB[16 * 260];
  const int til = blockIdx.x;
  const int t = threadIdx.x;
  if (til < 4) ((float4*)sums)[til * 1024 + t] = (float4){0.f, 0.f, 0.f, 0.f};

  const int r = t >> 6, j = t & 63;   // wave r = row r of tile; lane j
  const int row = til * 16 + r;
  const float4* __restrict__ aR = (const float4*)(im + (size_t)row * D_);
  const float4* __restrict__ bR = (const float4*)(cap + (size_t)row * D_);

  float4 a0 = aR[j], a1 = aR[j + 64], a2 = aR[j + 128], a3 = aR[j + 192];
  float4 b0 = bR[j], b1 = bR[j + 64], b2 = bR[j + 128], b3 = bR[j + 192];

  float ssa = a0.x * a0.x + a0.y * a0.y + a0.z * a0.z + a0.w * a0.w
            + a1.x * a1.x + a1.y * a1.y + a1.z * a1.z + a1.w * a1.w
            + a2.x * a2.x + a2.y * a2.y + a2.z * a2.z + a2.w * a2.w
            + a3.x * a3.x + a3.y * a3.y + a3.z * a3.z + a3.w * a3.w;
  float ssb = b0.x * b0.x + b0.y * b0.y + b0.z * b0.z + b0.w * b0.w
            + b1.x * b1.x + b1.y * b1.y + b1.z * b1.z + b1.w * b1.w
            + b2.x * b2.x + b2.y * b2.y + b2.z * b2.z + b2.w * b2.w
            + b3.x * b3.x + b3.y * b3.y + b3.z * b3.z + b3.w * b3.w;
  float dt  = a0.x * b0.x + a0.y * b0.y + a0.z * b0.z + a0.w * b0.w
            + a1.x * b1.x + a1.y * b1.y + a1.z * b1.z + a1.w * b1.w
            + a2.x * b2.x + a2.y * b2.y + a2.z * b2.z + a2.w * b2.w
            + a3.x * b3.x + a3.y * b3.y + a3.z * b3.z + a3.w * b3.w;
#pragma unroll
  for (int o = 1; o < 64; o <<= 1) {  // full-wave butterfly (row = 1 wave)
    ssa += __shfl_xor(ssa, o, 64);
    ssb += __shfl_xor(ssb, o, 64);
    dt  += __shfl_xor(dt, o, 64);
  }
  const float ra = rsqrtf(ssa), rb = rsqrtf(ssb);
  if (j == 0) diag[row] = dt * ra * rb * 10.0f;
  const float sa = ra * ENC_SCALE, sb = rb * ENC_SCALE;

#define CVT_ST(av, bv, ofs)                                                  \
  {                                                                          \
    int pa_ = __builtin_amdgcn_cvt_pk_fp8_f32(av.x * sa, av.y * sa, 0, false); \
    pa_ = __builtin_amdgcn_cvt_pk_fp8_f32(av.z * sa, av.w * sa, pa_, true);  \
    int pb_ = __builtin_amdgcn_cvt_pk_fp8_f32(bv.x * sb, bv.y * sb, 0, false); \
    pb_ = __builtin_amdgcn_cvt_pk_fp8_f32(bv.z * sb, bv.w * sb, pb_, true);  \
    ldsA[r * 260 + j + (ofs)] = (unsigned int)pa_;                           \
    ldsB[r * 260 + j + (ofs)] = (unsigned int)pb_;                           \
  }
  CVT_ST(a0, b0, 0)
  CVT_ST(a1, b1, 64)
  CVT_ST(a2, b2, 128)
  CVT_ST(a3, b3, 192)
#undef CVT_ST
  __syncthreads();

  // phase 3: thread t emits 16B granule q = t>>4 of row rp = t&15.
  // Shared derivation: c = q>>2, g = (q>>1)&1 (k-32-block), p = q&1,
  // row32 = ((til&1)<<4)+rp, lane slot = g*32 + row32.
  {
    const int q = t >> 4, rp = t & 15;
    const uint4 va = *(const uint4*)&ldsA[rp * 260 + q * 4];
    const uint4 vb = *(const uint4*)&ldsB[rp * 260 + q * 4];
    const int row32 = ((til & 1) << 4) + rp;
    const int slot = (((q >> 1) & 1) << 5) + row32;
    const size_t base = (size_t)(q >> 2) * CHUNK + (size_t)(til >> 1) * 2048;
    const size_t dA = base + (size_t)((q & 1) << 10) + (size_t)slot * 16;
    const size_t dB = base + (size_t)slot * 32 + (size_t)((q & 1) << 4);
    *(uint4*)((unsigned char*)imn + dA) = va;
    *(uint4*)((unsigned char*)capn + dB) = vb;
  }
}

// Kernel 2 [R17]: R5's B-direct idea with the occupancy restored. R5 failed
// because 128x64 wave tiles (128 AGPR + 112 VGPR = 240/wave unified) pinned
// the CU at 8 waves and depth-1 prefetch had no TLP to hide L2 latency.
// Now: 4-wave blocks (2Mx2N), wave 64x64 (acc[2][2] = 64 AGPR), tile
// 128x128, launch_bounds(256,3) -> ~150 regs -> 3 waves/SIMD = 3
// barrier-independent blocks/CU (12 waves). A (shared by 2 waves) via LDS
// ring-2 (8KB/chunk, 2 GLD16/thread); B direct L2->reg as single i32x8
// loads (new capn layout), double-buffered in named sets. Counted vmcnt(6)
// (= 2 A-GLD + 4 B-dwordx4 per chunk), never 0 in-loop.
__global__ __launch_bounds__(256, 3) void gemm_lse_k(
    const unsigned char* __restrict__ A,   // imn, fragment layout
    const unsigned char* __restrict__ B,   // capn, lane-32B layout
    float* __restrict__ rowsum, float* __restrict__ colsum) {
  __shared__ unsigned char lds[2][8192];  // ring-2 A tiles: 4 T32 x 2048B
  const int t = threadIdx.x;
  const int w = t >> 6, l = t & 63;
  const int l16 = l * 16;

  // XCD swizzle: 512-block chunk per XCD = 8 rowT x 64 colT (colT fastest).
  const int bid = blockIdx.x + (blockIdx.y << 6);     // 0..4095
  const int nid = (bid & 7) * 512 + (bid >> 3);       // bijective (4096%8==0)
  const int rowT = ((nid >> 9) << 3) + (nid & 7);     // 0..63  (128-row tiles)
  const int colT = (nid >> 3) & 63;                   // 0..63  (128-col tiles)

  const size_t baseA = (size_t)rowT * 8192;   // 4 T32-tiles x 2048B per chunk
  const size_t baseB = (size_t)colT * 8192;

  const int wr = w >> 1, wc = w & 1;  // 2M x 2N waves, 64x64 each

  // A staging: 8KB/chunk; thread t covers bytes t*16 and 4096+t*16 (linear).
  const unsigned char* __restrict__ srcA = A + baseA + t * 16;
  // B: wave wc owns T32 tiles wc*2+{0,1}; lane fragment = 32B contiguous.
  const unsigned char* __restrict__ srcB = B + baseB + wc * 4096 + l * 32;

#define STAGE(kc, buf)                                                       \
  {                                                                          \
    const unsigned char* ap = srcA + (size_t)(kc) * CHUNK;                   \
    GLD16(ap, &lds[buf][t * 16]);                                            \
    GLD16(ap + 4096, &lds[buf][4096 + t * 16]);                              \
  }

#define BLOAD(dst, kc)                                                       \
  {                                                                          \
    const unsigned char* bp = srcB + (size_t)(kc) * CHUNK;                   \
    dst[0] = *(const i32x8*)(bp);                                            \
    dst[1] = *(const i32x8*)(bp + 2048);                                     \
  }

  f32x16 acc[2][2];
#pragma unroll
  for (int m = 0; m < 2; ++m)
#pragma unroll
    for (int n = 0; n < 2; ++n)
#pragma unroll
      for (int r = 0; r < 16; ++r) acc[m][n][r] = 0.f;

  i32x8 bb0[2], bb1[2];  // named double-buffer (rule #20: no runtime index)

#define COMPUTE(buf, bset)                                                   \
  {                                                                          \
    const unsigned char* Lc = &lds[buf][0];                                  \
    i32x8 a_[2];                                                             \
    _Pragma("unroll")                                                        \
    for (int m = 0; m < 2; ++m) {                                            \
      i32x4 lo = *(const i32x4*)(Lc + (wr * 2 + m) * 2048 + l16);            \
      i32x4 hi = *(const i32x4*)(Lc + (wr * 2 + m) * 2048 + 1024 + l16);     \
      a_[m] = __builtin_shufflevector(lo, hi, 0, 1, 2, 3, 4, 5, 6, 7);       \
    }                                                                        \
    _Pragma("unroll")                                                        \
    for (int m = 0; m < 2; ++m)                                              \
      _Pragma("unroll")                                                      \
      for (int n = 0; n < 2; ++n)                                            \
        acc[m][n] = __builtin_amdgcn_mfma_scale_f32_32x32x64_f8f6f4(         \
            a_[m], bset[n], acc[m][n], 0, 0, 0, 0x7F7F7F7F, 0, 0x7F7F7F7F);  \
  }

  // prologue: chunk 0 in flight (2 GLD + 2 B i32x8 = 6 vmem ops)
  STAGE(0, 0)
  BLOAD(bb0, 0)

  // main loop, unrolled x2 for named B buffers. Per half: issue chunk
  // kc+1's 6 vmem ops, vmcnt(6) retires chunk kc's, barrier, compute,
  // barrier. STAGE(kc+1) writes the buffer freed by the previous compute's
  // end barrier (ring-2 discipline, proven R3/R4).
#pragma unroll 1
  for (int kt = 0; kt < 14; kt += 2) {
    STAGE(kt + 1, 1)
    BLOAD(bb1, kt + 1)
    asm volatile("s_waitcnt vmcnt(6)" ::: "memory");
    __builtin_amdgcn_s_barrier();
    COMPUTE(0, bb0)
    __builtin_amdgcn_s_barrier();
    STAGE(kt + 2, 0)
    BLOAD(bb0, kt + 2)
    asm volatile("s_waitcnt vmcnt(6)" ::: "memory");
    __builtin_amdgcn_s_barrier();
    COMPUTE(1, bb1)
    __builtin_amdgcn_s_barrier();
  }
  // tail: chunks 14 (bb0/buf0) and 15 (bb1/buf1)
  STAGE(15, 1)
  BLOAD(bb1, 15)
  asm volatile("s_waitcnt vmcnt(6)" ::: "memory");
  __builtin_amdgcn_s_barrier();
  COMPUTE(0, bb0)
  __builtin_amdgcn_s_barrier();
  asm volatile("s_waitcnt vmcnt(0)" ::: "memory");
  __builtin_amdgcn_s_barrier();
  COMPUTE(1, bb1)
#undef COMPUTE
#undef BLOAD
#undef STAGE

  // epilogue: exp (fixed-max LSE; |logit| <= 10, no overflow possible)
#pragma unroll
  for (int m = 0; m < 2; ++m)
#pragma unroll
    for (int n = 0; n < 2; ++n)
#pragma unroll
      for (int r = 0; r < 16; ++r)
        acc[m][n][r] = __expf(acc[m][n][r] * EPILOGUE_SCALE);

  // 32x32 C/D layout: col = lane&31, row = (reg&3)+8*(reg>>2)+4*(lane>>5)
  // [measured m74/m101]
  const int rowBase = rowT * 128 + wr * 64;
  const int colBase = colT * 128 + wc * 64;
#pragma unroll
  for (int m = 0; m < 2; ++m) {
    f32x16 s = acc[m][0] + acc[m][1];  // sum this wave's 64 cols elementwise
#pragma unroll
    for (int r = 0; r < 16; ++r) {
      float v = s[r];
      v += __shfl_xor(v, 1, 64);
      v += __shfl_xor(v, 2, 64);
      v += __shfl_xor(v, 4, 64);
      v += __shfl_xor(v, 8, 64);
      v += __shfl_xor(v, 16, 64);
      if ((l & 31) == 0)
        atomicAdd(&rowsum[rowBase + m * 32 + (r & 3) + 8 * (r >> 2) + 4 * (l >> 5)], v);
    }
  }
#pragma unroll
  for (int n = 0; n < 2; ++n) {
    float v = 0.f;
#pragma unroll
    for (int r = 0; r < 16; ++r) v += acc[0][n][r] + acc[1][n][r];
    v += __shfl_xor(v, 32, 64);  // combine the two row-half lane groups
    if (l < 32)
      atomicAdd(&colsum[colBase + n * 32 + l], v);
  }
}

// Kernel 3: scalar reduce. [unchanged]
__global__ __launch_bounds__(256) void finalize_k(
    const float* __restrict__ rowsum, const float* __restrict__ colsum,
    const float* __restrict__ diag, float* __restrict__ out) {
  const int t = threadIdx.x;
  float lse = 0.f, dg = 0.f;
  for (int i = t; i < N_; i += 256) {
    lse += __logf(rowsum[i]) + __logf(colsum[i]);
    dg += diag[i];
  }
#pragma unroll
  for (int o = 32; o > 0; o >>= 1) {
    lse += __shfl_down(lse, o, 64);
    dg  += __shfl_down(dg, o, 64);
  }
  __shared__ float red[2][4];
  const int w = t >> 6, l = t & 63;
  if (l == 0) { red[0][w] = lse; red[1][w] = dg; }
  __syncthreads();
  if (t == 0) {
    lse = red[0][0] + red[0][1] + red[0][2] + red[0][3];
    dg  = red[1][0] + red[1][1] + red[1][2] + red[1][3];
    out[0] = 0.5f * lse / (float)N_ - dg / (float)N_;
  }
}

extern "C" void kernel_launch(void* const* d_in, const int* in_sizes, int n_in,
                              void* d_out, int out_size, void* d_ws, size_t ws_size,
                              hipStream_t stream) {
  const float* im = (const float*)d_in[0];
  const float* cap = (const float*)d_in[1];
  float* out = (float*)d_out;
  char* ws = (char*)d_ws;
  unsigned char* imn = (unsigned char*)ws;                 // 8 MB fp8 (fragment layout)
  unsigned char* capn = imn + (size_t)N_ * D_;             // 8 MB fp8 (lane-32B layout)
  float* rowsum = (float*)(ws + 2 * (size_t)N_ * D_);
  float* colsum = rowsum + N_;
  float* diag = colsum + N_;

  normalize_k<<<512, 1024, 0, stream>>>(im, cap, (unsigned int*)imn,
                                        (unsigned int*)capn, diag, rowsum);
  gemm_lse_k<<<dim3(64, 64), 256, 0, stream>>>(imn, capn, rowsum, colsum);
  finalize_k<<<1, 256, 0, stream>>>(rowsum, colsum, diag, out);
}

// Round 7
// 190.274 us; speedup vs baseline: 1.0829x; 1.0673x over previous
//
#include <hip/hip_runtime.h>
#include <stdint.h>

#define N_ 8192
#define D_ 1024
// logit = dot(imn,capn)/T; fp8 operands pre-scaled by 16 -> acc = 256*dot
// (MX scales set to E8M0 1.0 -> identical numerics to plain fp8 MFMA)
#define EPILOGUE_SCALE (10.0f / 256.0f)
#define ENC_SCALE 16.0f
#define CHUNK 524288  // bytes of one K-chunk (64 K-bytes x 8192 rows): 256 T32-tiles x 2048B

typedef float f32x4 __attribute__((ext_vector_type(4)));
typedef float f32x16 __attribute__((ext_vector_type(16)));
typedef int i32x4 __attribute__((ext_vector_type(4)));
typedef int i32x8 __attribute__((ext_vector_type(8)));

// async global->LDS, 16B per lane, LDS dest = wave-uniform base + lane*16
#define GLD16(gsrc, ldst)                                                    \
  __builtin_amdgcn_global_load_lds(                                          \
      (const __attribute__((address_space(1))) unsigned int*)(gsrc),         \
      (__attribute__((address_space(3))) unsigned int*)(ldst), 16, 0, 0)

// R4 fragment layout (32x32x64 f8f6f4 family pattern), both operands, 8MB:
//   byte addr = c*CHUNK + T32*2048 + p*1024 + l*16 + o   (c:K-chunk of 64,
//   T32: 32-row tile, p: K-16B-half, l: lane, o in [0,16))
//   holds row = T32*32 + (l&31), k = c*64 + (l>>5)*32 + p*16 + o.

// Kernel 1 [R7 rewrite — granularity]: old 1024-thread/16-wave blocks = one
// single-shot GPU fill (512 blocks), 2 slots/CU, wall ~= one block's full
// serial chain (HBM latency -> 18-stage shuffle reduce -> LDS round-trip ->
// scattered store). Now 256 threads / 4 waves / 4 rows per block, 2048
// blocks -> 8 independent resident blocks/CU; cross-block phase skew hides
// per-phase latency. Algorithm and output layout unchanged.
__global__ __launch_bounds__(256) void normalize_k(
    const float* __restrict__ im, const float* __restrict__ cap,
    unsigned int* __restrict__ imn, unsigned int* __restrict__ capn,
    float* __restrict__ diag, float* __restrict__ sums /* rowsum|colsum */) {
  __shared__ unsigned int ldsA[4 * 260];  // stride 260: 16B-aligned rows
  __shared__ unsigned int ldsB[4 * 260];
  const int b = blockIdx.x;
  const int t = threadIdx.x;
  // zero rowsum|colsum: 16 blocks x 256 threads x float4 = 16384 floats
  if (b < 16) ((float4*)sums)[b * 256 + t] = (float4){0.f, 0.f, 0.f, 0.f};

  const int r = t >> 6, j = t & 63;   // wave r = row r of block; lane j
  const int row = b * 4 + r;
  const float4* __restrict__ aR = (const float4*)(im + (size_t)row * D_);
  const float4* __restrict__ bR = (const float4*)(cap + (size_t)row * D_);

  float4 a0 = aR[j], a1 = aR[j + 64], a2 = aR[j + 128], a3 = aR[j + 192];
  float4 b0 = bR[j], b1 = bR[j + 64], b2 = bR[j + 128], b3 = bR[j + 192];

  float ssa = a0.x * a0.x + a0.y * a0.y + a0.z * a0.z + a0.w * a0.w
            + a1.x * a1.x + a1.y * a1.y + a1.z * a1.z + a1.w * a1.w
            + a2.x * a2.x + a2.y * a2.y + a2.z * a2.z + a2.w * a2.w
            + a3.x * a3.x + a3.y * a3.y + a3.z * a3.z + a3.w * a3.w;
  float ssb = b0.x * b0.x + b0.y * b0.y + b0.z * b0.z + b0.w * b0.w
            + b1.x * b1.x + b1.y * b1.y + b1.z * b1.z + b1.w * b1.w
            + b2.x * b2.x + b2.y * b2.y + b2.z * b2.z + b2.w * b2.w
            + b3.x * b3.x + b3.y * b3.y + b3.z * b3.z + b3.w * b3.w;
  float dt  = a0.x * b0.x + a0.y * b0.y + a0.z * b0.z + a0.w * b0.w
            + a1.x * b1.x + a1.y * b1.y + a1.z * b1.z + a1.w * b1.w
            + a2.x * b2.x + a2.y * b2.y + a2.z * b2.z + a2.w * b2.w
            + a3.x * b3.x + a3.y * b3.y + a3.z * b3.z + a3.w * b3.w;
#pragma unroll
  for (int o = 1; o < 64; o <<= 1) {  // full-wave butterfly (row = 1 wave)
    ssa += __shfl_xor(ssa, o, 64);
    ssb += __shfl_xor(ssb, o, 64);
    dt  += __shfl_xor(dt, o, 64);
  }
  const float ra = rsqrtf(ssa), rb = rsqrtf(ssb);
  if (j == 0) diag[row] = dt * ra * rb * 10.0f;
  const float sa = ra * ENC_SCALE, sb = rb * ENC_SCALE;

#define CVT_ST(av, bv, ofs)                                                  \
  {                                                                          \
    int pa_ = __builtin_amdgcn_cvt_pk_fp8_f32(av.x * sa, av.y * sa, 0, false); \
    pa_ = __builtin_amdgcn_cvt_pk_fp8_f32(av.z * sa, av.w * sa, pa_, true);  \
    int pb_ = __builtin_amdgcn_cvt_pk_fp8_f32(bv.x * sb, bv.y * sb, 0, false); \
    pb_ = __builtin_amdgcn_cvt_pk_fp8_f32(bv.z * sb, bv.w * sb, pb_, true);  \
    ldsA[r * 260 + j + (ofs)] = (unsigned int)pa_;                           \
    ldsB[r * 260 + j + (ofs)] = (unsigned int)pb_;                           \
  }
  CVT_ST(a0, b0, 0)
  CVT_ST(a1, b1, 64)
  CVT_ST(a2, b2, 128)
  CVT_ST(a3, b3, 192)
#undef CVT_ST
  __syncthreads();

  // phase 3: wave rp emits the 64 16B granules of row b*4+rp.
  // q -> c = q>>2, g = (q>>1)&1 (k-32-block), p = q&1; slot = g*32+(row&31).
  {
    const int rp = t >> 6, q = t & 63;
    const uint4 va = *(const uint4*)&ldsA[rp * 260 + q * 4];
    const uint4 vb = *(const uint4*)&ldsB[rp * 260 + q * 4];
    const int rowp = b * 4 + rp;
    const int slot = (((q >> 1) & 1) << 5) + (rowp & 31);
    const size_t d = (size_t)(q >> 2) * CHUNK + (size_t)(rowp >> 5) * 2048
                   + (size_t)((q & 1) << 10) + (size_t)slot * 16;
    *(uint4*)((unsigned char*)imn + d) = va;
    *(uint4*)((unsigned char*)capn + d) = vb;
  }
}

// Kernel 2 [R4 verbatim — 93.7 us proven champion; R5/R6 B-direct variants
// both regressed (L2-stream + depth-1 latency unhidden), reverted]:
// MX-scaled fp8 GEMM on ring-2/vmcnt(3)/2-barrier skeleton. 256x128 block
// tile, 8 waves (4Mx2N) of 64x64 (2x2 of 32x32 -> acc 64 VGPR). BK=64 =
// 1 K-chunk/iter, 16 iters. LDS 2x24KB.
__global__ __launch_bounds__(512, 4) void gemm_lse_k(
    const unsigned char* __restrict__ A,   // fragment-layout imn
    const unsigned char* __restrict__ B,   // fragment-layout capn
    float* __restrict__ rowsum, float* __restrict__ colsum) {
  __shared__ unsigned char lds[2][24576];  // ring-2: [A 16KB | B 8KB] each
  const int t = threadIdx.x;
  const int w = t >> 6, l = t & 63;
  const int l16 = l * 16;

  // XCD/L2 swizzle: 256-block chunk per XCD.
  const int bid = blockIdx.x + (blockIdx.y << 5);     // 0..2047
  const int nid = (bid & 7) * 256 + (bid >> 3);       // bijective (2048%8==0)
  const int rowT = ((nid >> 8) << 2) + (nid & 3);     // 0..31
  const int colT = (nid >> 2) & 63;                   // 0..63

  const size_t baseA = (size_t)rowT * 16384;  // 8 T32-tiles x 2048B per chunk
  const size_t baseB = (size_t)colT * 8192;   // 4 T32-tiles x 2048B per chunk

  // staging: 24KB/tile = 24 x 1KB chunks; wave w owns 3 (mixed A/B).
  const unsigned char* src[3];
  int ldsOff[3];
#pragma unroll
  for (int c = 0; c < 3; ++c) {
    const int o = w * 3072 + c * 1024;
    ldsOff[c] = o;
    src[c] = (o < 16384) ? (A + baseA + o + l16)
                         : (B + baseB + (o - 16384) + l16);
  }

#define STAGE(kc, buf)                                                       \
  {                                                                          \
    const size_t kofs = (size_t)(kc) * CHUNK;                                \
    GLD16(src[0] + kofs, &lds[buf][ldsOff[0]]);                              \
    GLD16(src[1] + kofs, &lds[buf][ldsOff[1]]);                              \
    GLD16(src[2] + kofs, &lds[buf][ldsOff[2]]);                              \
  }

  const int wr = w >> 1, wc = w & 1;  // 4M x 2N waves, 64x64 each (2x2 T32)

  f32x16 acc[2][2];
#pragma unroll
  for (int m = 0; m < 2; ++m)
#pragma unroll
    for (int n = 0; n < 2; ++n)
#pragma unroll
      for (int r = 0; r < 16; ++r) acc[m][n][r] = 0.f;

#define COMPUTE(buf)                                                         \
  {                                                                          \
    const unsigned char* Lc = &lds[buf][0];                                  \
    i32x8 a_[2], b_[2];                                                      \
    _Pragma("unroll")                                                        \
    for (int m = 0; m < 2; ++m) {                                            \
      i32x4 lo = *(const i32x4*)(Lc + (wr * 2 + m) * 2048 + l16);            \
      i32x4 hi = *(const i32x4*)(Lc + (wr * 2 + m) * 2048 + 1024 + l16);     \
      a_[m] = __builtin_shufflevector(lo, hi, 0, 1, 2, 3, 4, 5, 6, 7);       \
    }                                                                        \
    _Pragma("unroll")                                                        \
    for (int n = 0; n < 2; ++n) {                                            \
      i32x4 lo = *(const i32x4*)(Lc + 16384 + (wc * 2 + n) * 2048 + l16);    \
      i32x4 hi = *(const i32x4*)(Lc + 16384 + (wc * 2 + n) * 2048 + 1024 + l16); \
      b_[n] = __builtin_shufflevector(lo, hi, 0, 1, 2, 3, 4, 5, 6, 7);       \
    }                                                                        \
    _Pragma("unroll")                                                        \
    for (int m = 0; m < 2; ++m)                                              \
      _Pragma("unroll")                                                      \
      for (int n = 0; n < 2; ++n)                                            \
        acc[m][n] = __builtin_amdgcn_mfma_scale_f32_32x32x64_f8f6f4(         \
            a_[m], b_[n], acc[m][n], 0, 0, 0, 0x7F7F7F7F, 0, 0x7F7F7F7F);    \
  }

  // prologue: chunk 0 in flight (3 loads/wave)
  STAGE(0, 0)

  // main loop: after STAGE, FIFO = {kc:3, kc+1:3}; vmcnt(3) retires chunk
  // kc, leaves kc+1 in flight across both barriers.
#pragma unroll 1
  for (int kt = 0; kt < 15; ++kt) {
    STAGE(kt + 1, (kt + 1) & 1)
    asm volatile("s_waitcnt vmcnt(3)" ::: "memory");
    __builtin_amdgcn_s_barrier();
    COMPUTE(kt & 1)
    __builtin_amdgcn_s_barrier();
  }
  asm volatile("s_waitcnt vmcnt(0)" ::: "memory");
  __builtin_amdgcn_s_barrier();
  COMPUTE(1)
#undef COMPUTE
#undef STAGE

  // epilogue: exp (fixed-max LSE; |logit| <= 10, no overflow possible)
#pragma unroll
  for (int m = 0; m < 2; ++m)
#pragma unroll
    for (int n = 0; n < 2; ++n)
#pragma unroll
      for (int r = 0; r < 16; ++r)
        acc[m][n][r] = __expf(acc[m][n][r] * EPILOGUE_SCALE);

  // 32x32 C/D layout: col = lane&31, row = (reg&3)+8*(reg>>2)+4*(lane>>5)
  // [measured m74/m101]
  const int rowBase = rowT * 256 + wr * 64;
  const int colBase = colT * 128 + wc * 64;
#pragma unroll
  for (int m = 0; m < 2; ++m) {
    f32x16 s = acc[m][0] + acc[m][1];  // cols sum elementwise across n-tiles
#pragma unroll
    for (int r = 0; r < 16; ++r) {
      float v = s[r];
      v += __shfl_xor(v, 1, 64);
      v += __shfl_xor(v, 2, 64);
      v += __shfl_xor(v, 4, 64);
      v += __shfl_xor(v, 8, 64);
      v += __shfl_xor(v, 16, 64);
      if ((l & 31) == 0)
        atomicAdd(&rowsum[rowBase + m * 32 + (r & 3) + 8 * (r >> 2) + 4 * (l >> 5)], v);
    }
  }
#pragma unroll
  for (int n = 0; n < 2; ++n) {
    float v = 0.f;
#pragma unroll
    for (int r = 0; r < 16; ++r) v += acc[0][n][r] + acc[1][n][r];
    v += __shfl_xor(v, 32, 64);  // combine the two row-half lane groups
    if (l < 32)
      atomicAdd(&colsum[colBase + n * 32 + l], v);
  }
}

// Kernel 3: scalar reduce. [unchanged]
__global__ __launch_bounds__(256) void finalize_k(
    const float* __restrict__ rowsum, const float* __restrict__ colsum,
    const float* __restrict__ diag, float* __restrict__ out) {
  const int t = threadIdx.x;
  float lse = 0.f, dg = 0.f;
  for (int i = t; i < N_; i += 256) {
    lse += __logf(rowsum[i]) + __logf(colsum[i]);
    dg += diag[i];
  }
#pragma unroll
  for (int o = 32; o > 0; o >>= 1) {
    lse += __shfl_down(lse, o, 64);
    dg  += __shfl_down(dg, o, 64);
  }
  __shared__ float red[2][4];
  const int w = t >> 6, l = t & 63;
  if (l == 0) { red[0][w] = lse; red[1][w] = dg; }
  __syncthreads();
  if (t == 0) {
    lse = red[0][0] + red[0][1] + red[0][2] + red[0][3];
    dg  = red[1][0] + red[1][1] + red[1][2] + red[1][3];
    out[0] = 0.5f * lse / (float)N_ - dg / (float)N_;
  }
}

extern "C" void kernel_launch(void* const* d_in, const int* in_sizes, int n_in,
                              void* d_out, int out_size, void* d_ws, size_t ws_size,
                              hipStream_t stream) {
  const float* im = (const float*)d_in[0];
  const float* cap = (const float*)d_in[1];
  float* out = (float*)d_out;
  char* ws = (char*)d_ws;
  unsigned char* imn = (unsigned char*)ws;                 // 8 MB fp8 (fragment layout)
  unsigned char* capn = imn + (size_t)N_ * D_;             // 8 MB fp8 (fragment layout)
  float* rowsum = (float*)(ws + 2 * (size_t)N_ * D_);
  float* colsum = rowsum + N_;
  float* diag = colsum + N_;

  normalize_k<<<2048, 256, 0, stream>>>(im, cap, (unsigned int*)imn,
                                        (unsigned int*)capn, diag, rowsum);
  gemm_lse_k<<<dim3(32, 64), 512, 0, stream>>>(imn, capn, rowsum, colsum);
  finalize_k<<<1, 256, 0, stream>>>(rowsum, colsum, diag, out);
}